// Round 1
// baseline (199.781 us; speedup 1.0000x reference)
//
#include <hip/hip_runtime.h>
#include <hip/hip_fp16.h>

// ---------------------------------------------------------------------------
// Fused edge-MLP:  score = (relu(relu([h[src]|h[dst]]W1+b1)W2+b2))W3+b3
// Strategy: persistent MFMA kernel, fp16 inputs / f32 accum.
//   * Weights pre-packed (pack_w_kernel) into per-lane MFMA B-fragments and
//     held in VGPRs for the whole kernel (W1:64, W2:32, W3:16 VGPRs/lane).
//   * h pre-converted to fp16 (conv_h_kernel) into d_ws.
//   * All LDS tiles are FRAGMENT-PACKED: frag for (k-block kk, row-block rb)
//     lives at [(kk*4+rb)*64 + lane]*16B, lane = 16*g + (row&15),
//     element j of lane = matrix[row][32*kk + 8*g + j].
//     A and B use the SAME k-permutation -> permutation of the contraction
//     index cancels inside MFMA; only the verified C layout matters
//     (col = lane&15, row = 4*(lane>>4)+reg).
//   * Pipeline: gather loads for tile t+1 issued right after layer-1 reads of
//     X(t); LDS commit at end of tile (issue-early / write-late).
// ---------------------------------------------------------------------------

typedef _Float16 half8 __attribute__((ext_vector_type(8)));
typedef float    f32x4 __attribute__((ext_vector_type(4)));

#define N_NODES_C 100000
#define N_EDGES_C 800000
#define NT        12500       // 800000 / 64 edge tiles
#define GRID_MAIN 512

#define W1F_OFF   0           // 32768 fp16 = 65536 B
#define W2F_OFF   65536       // 16384 fp16 = 32768 B
#define W3F_OFF   98304       //  2048 fp16 =  4096 B
#define H16_OFF   131072
#define H16_BYTES (N_NODES_C * 128 * 2)     // 25,600,000
#define WS_NEED   ((size_t)H16_OFF + (size_t)H16_BYTES)

#define MFMA16(a, b, c) __builtin_amdgcn_mfma_f32_16x16x32_f16((a), (b), (c), 0, 0, 0)

// --------------------------- pre-kernels -----------------------------------

__global__ void conv_h_kernel(const float* __restrict__ h, _Float16* __restrict__ h16, int n8) {
    int stride = gridDim.x * blockDim.x;
    for (int i = blockIdx.x * blockDim.x + threadIdx.x; i < n8; i += stride) {
        const float4* p = (const float4*)h + 2 * (size_t)i;
        float4 a = p[0], b = p[1];
        half8 o;
        o[0] = (_Float16)a.x; o[1] = (_Float16)a.y; o[2] = (_Float16)a.z; o[3] = (_Float16)a.w;
        o[4] = (_Float16)b.x; o[5] = (_Float16)b.y; o[6] = (_Float16)b.z; o[7] = (_Float16)b.w;
        ((half8*)h16)[i] = o;
    }
}

// Pack weights into fragment order:
//  w1f: [t:8][kk:8][lane:64][j:8]  elem = W1[32*kk + 8*(lane>>4) + j][16*t + (lane&15)]
//  w2f: [t:8][kk:4][lane:64][j:8]  elem = W2[...same...]
//  w3f: [kk:4][lane:64][j:8]       elem = (n<2) ? W3[k][n] : 0,  n = lane&15
__global__ void pack_w_kernel(const float* __restrict__ W1, const float* __restrict__ W2,
                              const float* __restrict__ W3, char* __restrict__ wsb) {
    int i = blockIdx.x * blockDim.x + threadIdx.x;
    _Float16* w1f = (_Float16*)(wsb + W1F_OFF);
    _Float16* w2f = (_Float16*)(wsb + W2F_OFF);
    _Float16* w3f = (_Float16*)(wsb + W3F_OFF);
    if (i < 32768) {
        int j = i & 7, lx = (i >> 3) & 63, kk = (i >> 9) & 7, t = i >> 12;
        int k = 32 * kk + 8 * (lx >> 4) + j, n = 16 * t + (lx & 15);
        w1f[i] = (_Float16)W1[k * 128 + n];
    }
    if (i < 16384) {
        int j = i & 7, lx = (i >> 3) & 63, kk = (i >> 9) & 3, t = i >> 11;
        int k = 32 * kk + 8 * (lx >> 4) + j, n = 16 * t + (lx & 15);
        w2f[i] = (_Float16)W2[k * 128 + n];
    }
    if (i < 2048) {
        int j = i & 7, lx = (i >> 3) & 63, kk = i >> 9;
        int k = 32 * kk + 8 * (lx >> 4) + j, n = lx & 15;
        w3f[i] = (n < 2) ? (_Float16)W3[k * 2 + n] : (_Float16)0.0f;
    }
}

// --------------------------- main kernel -----------------------------------

template <bool USE16>
__device__ inline half8 ldfrag(const float* __restrict__ h, const half8* __restrict__ h16,
                               int idx, int kk, int g) {
    if constexpr (USE16) {
        // h16 row = 16 half8 chunks; chunk = (kk&3)*4 + g  covers k-half bytes
        return h16[idx * 16 + (kk & 3) * 4 + g];
    } else {
        const float4* p = (const float4*)(h + (size_t)idx * 128 + (kk & 3) * 32 + g * 8);
        float4 a = p[0], b = p[1];
        half8 o;
        o[0] = (_Float16)a.x; o[1] = (_Float16)a.y; o[2] = (_Float16)a.z; o[3] = (_Float16)a.w;
        o[4] = (_Float16)b.x; o[5] = (_Float16)b.y; o[6] = (_Float16)b.z; o[7] = (_Float16)b.w;
        return o;
    }
}

template <bool USE16>
__global__ __launch_bounds__(256, 2) void edge_mlp_kernel(
    const float* __restrict__ h,
    const int*   __restrict__ src,
    const int*   __restrict__ dst,
    const float* __restrict__ b1,
    const float* __restrict__ b2,
    const float* __restrict__ b3,
    const char*  __restrict__ wsb,
    float*       __restrict__ out) {
    // Fragment-packed LDS tiles (all reads are conflict-free ds_read_b128)
    __shared__ half8 Xp [32 * 64];   // 32 KiB : [kk:8][rb:4][lane]  (K=256)
    __shared__ half8 Y1p[16 * 64];   // 16 KiB : [kk:4][rb:4][lane]  (K=128)
    __shared__ half8 Y2p[16 * 64];   // 16 KiB

    const int tid = threadIdx.x;
    const int w = tid >> 6, l = tid & 63;
    const int g = l >> 4, rr = l & 15;
    const int ghalf = rr >> 3, j7 = rr & 7;

    // ---- persistent weight fragments (per-wave N-slice: cols [32w,32w+32))
    half8 W1F[2][8], W2F[2][4], W3F[4];
    {
        const half8* p1 = (const half8*)(wsb + W1F_OFF);
        const half8* p2 = (const half8*)(wsb + W2F_OFF);
        const half8* p3 = (const half8*)(wsb + W3F_OFF);
#pragma unroll
        for (int nt = 0; nt < 2; ++nt)
#pragma unroll
            for (int kk = 0; kk < 8; ++kk)
                W1F[nt][kk] = p1[((w * 2 + nt) * 8 + kk) * 64 + l];
#pragma unroll
        for (int nt = 0; nt < 2; ++nt)
#pragma unroll
            for (int kk = 0; kk < 4; ++kk)
                W2F[nt][kk] = p2[((w * 2 + nt) * 4 + kk) * 64 + l];
#pragma unroll
        for (int kk = 0; kk < 4; ++kk)
            W3F[kk] = p3[kk * 64 + l];
    }
    float b1r[2], b2r[2];
    b1r[0] = b1[w * 32 + rr];      b1r[1] = b1[w * 32 + 16 + rr];
    b2r[0] = b2[w * 32 + rr];      b2r[1] = b2[w * 32 + 16 + rr];
    const float b3r = (rr < 2) ? b3[rr] : 0.0f;

    const half8* h16 = (const half8*)(wsb + H16_OFF);
    _Float16* y1h = (_Float16*)Y1p;
    _Float16* y2h = (_Float16*)Y2p;

    int   idxn[8];
    half8 xt[8];

    int tile = blockIdx.x;
    // ---- prime first tile (synchronous gather)
#pragma unroll
    for (int i = 0; i < 8; i++) {
        int bidx = w * 8 + i, kk = bidx >> 2;
        int e = ((i & 3) << 4) + rr;
        int id = (kk < 4 ? src : dst)[tile * 64 + e];
        xt[i] = ldfrag<USE16>(h, h16, id, kk, g);
    }
#pragma unroll
    for (int i = 0; i < 8; i++) Xp[(w * 8 + i) * 64 + l] = xt[i];
    {
        int t1 = tile + GRID_MAIN; if (t1 >= NT) t1 = NT - 1;
#pragma unroll
        for (int i = 0; i < 8; i++) {
            int bidx = w * 8 + i, kk = bidx >> 2;
            int e = ((i & 3) << 4) + rr;
            idxn[i] = (kk < 4 ? src : dst)[t1 * 64 + e];
        }
    }
    __syncthreads();

    for (; tile < NT; tile += GRID_MAIN) {
        // -------- layer 1: [64,256] x [256,32(per wave)] --------
        f32x4 acc1[4][2];
#pragma unroll
        for (int mt = 0; mt < 4; ++mt) {
            acc1[mt][0] = f32x4{0.f, 0.f, 0.f, 0.f};
            acc1[mt][1] = f32x4{0.f, 0.f, 0.f, 0.f};
        }
#pragma unroll
        for (int kk = 0; kk < 8; ++kk) {
            half8 a[4];
#pragma unroll
            for (int mt = 0; mt < 4; ++mt) a[mt] = Xp[(kk * 4 + mt) * 64 + l];
#pragma unroll
            for (int mt = 0; mt < 4; ++mt) {
                acc1[mt][0] = MFMA16(a[mt], W1F[0][kk], acc1[mt][0]);
                acc1[mt][1] = MFMA16(a[mt], W1F[1][kk], acc1[mt][1]);
            }
        }
        // issue gather for tile+GRID (latency hidden under layers 2/3)
#pragma unroll
        for (int i = 0; i < 8; i++) {
            int kk = (w * 8 + i) >> 2;
            xt[i] = ldfrag<USE16>(h, h16, idxn[i], kk, g);
        }
        {   // prefetch indices for tile+2*GRID
            int t2 = tile + 2 * GRID_MAIN; if (t2 >= NT) t2 = NT - 1;
#pragma unroll
            for (int i = 0; i < 8; i++) {
                int bidx = w * 8 + i, kk = bidx >> 2;
                int e = ((i & 3) << 4) + rr;
                idxn[i] = (kk < 4 ? src : dst)[t2 * 64 + e];
            }
        }
        // epilogue 1: bias+relu+cvt -> fragment-packed Y1
#pragma unroll
        for (int mt = 0; mt < 4; ++mt)
#pragma unroll
            for (int nt = 0; nt < 2; ++nt) {
                float bb = b1r[nt];
#pragma unroll
                for (int r = 0; r < 4; ++r) {
                    float v = acc1[mt][nt][r] + bb;
                    v = v > 0.f ? v : 0.f;
                    y1h[(((w * 4 + mt) * 64 + 16 * (2 * nt + ghalf) + 4 * g + r) << 3) + j7] =
                        (_Float16)v;
                }
            }
        __syncthreads();

        // -------- layer 2: [64,128] x [128,32] --------
        f32x4 acc2[4][2];
#pragma unroll
        for (int mt = 0; mt < 4; ++mt) {
            acc2[mt][0] = f32x4{0.f, 0.f, 0.f, 0.f};
            acc2[mt][1] = f32x4{0.f, 0.f, 0.f, 0.f};
        }
#pragma unroll
        for (int kk = 0; kk < 4; ++kk) {
            half8 a[4];
#pragma unroll
            for (int mt = 0; mt < 4; ++mt) a[mt] = Y1p[(kk * 4 + mt) * 64 + l];
#pragma unroll
            for (int mt = 0; mt < 4; ++mt) {
                acc2[mt][0] = MFMA16(a[mt], W2F[0][kk], acc2[mt][0]);
                acc2[mt][1] = MFMA16(a[mt], W2F[1][kk], acc2[mt][1]);
            }
        }
        // epilogue 2 -> fragment-packed Y2
#pragma unroll
        for (int mt = 0; mt < 4; ++mt)
#pragma unroll
            for (int nt = 0; nt < 2; ++nt) {
                float bb = b2r[nt];
#pragma unroll
                for (int r = 0; r < 4; ++r) {
                    float v = acc2[mt][nt][r] + bb;
                    v = v > 0.f ? v : 0.f;
                    y2h[(((w * 4 + mt) * 64 + 16 * (2 * nt + ghalf) + 4 * g + r) << 3) + j7] =
                        (_Float16)v;
                }
            }
        __syncthreads();

        // -------- layer 3: [16(per wave),128] x [128,2] --------
        f32x4 acc3 = {0.f, 0.f, 0.f, 0.f};
#pragma unroll
        for (int kk = 0; kk < 4; ++kk) {
            half8 a = Y2p[(kk * 4 + w) * 64 + l];
            acc3 = MFMA16(a, W3F[kk], acc3);
        }
        if (rr < 2) {
#pragma unroll
            for (int r = 0; r < 4; ++r) {
                int m = w * 16 + 4 * g + r;
                out[(tile * 64 + m) * 2 + rr] = acc3[r] + b3r;
            }
        }
        // commit staged X(tile+GRID); safe: all waves passed epi1-barrier
#pragma unroll
        for (int i = 0; i < 8; i++) Xp[(w * 8 + i) * 64 + l] = xt[i];
        __syncthreads();
    }
}

// --------------------------- launch ----------------------------------------

extern "C" void kernel_launch(void* const* d_in, const int* in_sizes, int n_in,
                              void* d_out, int out_size, void* d_ws, size_t ws_size,
                              hipStream_t stream) {
    const float* h  = (const float*)d_in[0];
    const int*   src = (const int*)d_in[1];
    const int*   dst = (const int*)d_in[2];
    const float* W1 = (const float*)d_in[3];
    const float* b1 = (const float*)d_in[4];
    const float* W2 = (const float*)d_in[5];
    const float* b2 = (const float*)d_in[6];
    const float* W3 = (const float*)d_in[7];
    const float* b3 = (const float*)d_in[8];
    char*  wsb = (char*)d_ws;
    float* out = (float*)d_out;
    (void)in_sizes; (void)n_in; (void)out_size;

    pack_w_kernel<<<128, 256, 0, stream>>>(W1, W2, W3, wsb);
    if (ws_size >= WS_NEED) {
        conv_h_kernel<<<2048, 256, 0, stream>>>(h, (_Float16*)(wsb + H16_OFF),
                                                N_NODES_C * 128 / 8);
        edge_mlp_kernel<true><<<GRID_MAIN, 256, 0, stream>>>(h, src, dst, b1, b2, b3, wsb, out);
    } else {
        edge_mlp_kernel<false><<<GRID_MAIN, 256, 0, stream>>>(h, src, dst, b1, b2, b3, wsb, out);
    }
}